// Round 15
// baseline (571.153 us; speedup 1.0000x reference)
//
#include <hip/hip_runtime.h>
#include <hip/hip_bf16.h>

typedef _Float16 f16x8 __attribute__((ext_vector_type(8)));
typedef _Float16 f16x4 __attribute__((ext_vector_type(4)));
typedef float    f32x4 __attribute__((ext_vector_type(4)));

constexpr int BB = 4;
constexpr int CH = 128;
constexpr int PC = 64;
constexpr int NN = 4096;

// ---------------------------------------------------------------------------
// DIAGNOSTIC ROUND (both kernels rep-looped so each dispatch > 165 us and
// surfaces its own rocprof counters above the harness fills).
// proj: r14 body x REP_P (idempotent re-stores). gram: r14 body x REP_G.
// ---------------------------------------------------------------------------
constexpr int REP_P = 32;
constexpr int REP_G = 5;

__global__ __launch_bounds__(256) void proj_kernel(
    const float* __restrict__ pos_bot,  // [B,64,N]
    const float* __restrict__ corr,     // [B,128,N]
    const float* __restrict__ Wp,       // [64,64]
    const float* __restrict__ bp,       // [64]
    const float* __restrict__ Wv,       // [128,128]
    const float* __restrict__ bv,       // [128]
    _Float16* __restrict__ xbuf,        // [B,N,64]
    float*    __restrict__ sq,          // [B,N]
    float*    __restrict__ eqF)         // [B,N,128]
{
    const int tid  = threadIdx.x;
    const int wid  = tid >> 6;
    const int lane = tid & 63;
    const int l15  = lane & 15;
    const int lg   = lane >> 4;
    const int b    = blockIdx.y & 3;
    const int n    = blockIdx.x * 16 + l15;

    __shared__ float psum[4][16];

    for (int rep = 0; rep < REP_P; ++rep) {
        asm volatile("" ::: "memory");   // force full re-execution per rep

        if ((blockIdx.y >> 2) == 0) {
            const int mt = wid;
            f16x8 wf[2], pb[2];
#pragma unroll
            for (int ks = 0; ks < 2; ++ks) {
                const float* wp = Wp + (mt * 16 + l15) * PC + ks * 32 + lg * 8;
                f32x4 w0 = *reinterpret_cast<const f32x4*>(wp);
                f32x4 w1 = *reinterpret_cast<const f32x4*>(wp + 4);
                f16x8 f;
#pragma unroll
                for (int e = 0; e < 4; ++e) { f[e] = (_Float16)w0[e]; f[e + 4] = (_Float16)w1[e]; }
                wf[ks] = f;
                f16x8 g;
#pragma unroll
                for (int e = 0; e < 8; ++e) {
                    const int c = ks * 32 + lg * 8 + e;
                    g[e] = (_Float16)pos_bot[((size_t)(b * PC + c)) * NN + n];
                }
                pb[ks] = g;
            }

            f32x4 acc = {0.f, 0.f, 0.f, 0.f};
            acc = __builtin_amdgcn_mfma_f32_16x16x32_f16(wf[0], pb[0], acc, 0, 0, 0);
            acc = __builtin_amdgcn_mfma_f32_16x16x32_f16(wf[1], pb[1], acc, 0, 0, 0);

            float partial = 0.f;
            f16x4 h4;
#pragma unroll
            for (int r = 0; r < 4; ++r) {
                const int o = mt * 16 + lg * 4 + r;
                const float v = acc[r] + bp[o];
                const _Float16 h = (_Float16)v;
                h4[r] = h;
                const float hf = (float)h;
                partial = fmaf(hf, hf, partial);
            }
            *reinterpret_cast<f16x4*>(xbuf + ((size_t)(b * NN + n)) * PC + mt * 16 + lg * 4) = h4;

            partial += __shfl_xor(partial, 16);
            partial += __shfl_xor(partial, 32);
            if (lane < 16) psum[wid][l15] = partial;
            __syncthreads();
            if (tid < 16)
                sq[b * NN + blockIdx.x * 16 + tid] =
                    psum[0][tid] + psum[1][tid] + psum[2][tid] + psum[3][tid];
            __syncthreads();   // keep psum reuse safe across reps
            continue;
        }

        f16x8 cb[4];
#pragma unroll
        for (int ks = 0; ks < 4; ++ks) {
            f16x8 g;
#pragma unroll
            for (int e = 0; e < 8; ++e) {
                const int c = ks * 32 + lg * 8 + e;
                g[e] = (_Float16)corr[((size_t)(b * CH + c)) * NN + n];
            }
            cb[ks] = g;
        }
#pragma unroll
        for (int half = 0; half < 2; ++half) {
            const int ot = wid + half * 4;
            f32x4 acc = {0.f, 0.f, 0.f, 0.f};
#pragma unroll
            for (int ks = 0; ks < 4; ++ks) {
                const float* wv = Wv + (ot * 16 + l15) * CH + ks * 32 + lg * 8;
                f32x4 w0 = *reinterpret_cast<const f32x4*>(wv);
                f32x4 w1 = *reinterpret_cast<const f32x4*>(wv + 4);
                f16x8 f;
#pragma unroll
                for (int e = 0; e < 4; ++e) { f[e] = (_Float16)w0[e]; f[e + 4] = (_Float16)w1[e]; }
                acc = __builtin_amdgcn_mfma_f32_16x16x32_f16(f, cb[ks], acc, 0, 0, 0);
            }
            f32x4 o4;
#pragma unroll
            for (int r = 0; r < 4; ++r) o4[r] = acc[r] + bv[ot * 16 + lg * 4 + r];
            __builtin_nontemporal_store(
                o4, reinterpret_cast<f32x4*>(eqF + ((size_t)(b * NN + n)) * CH + ot * 16 + lg * 4));
        }
    }
}

__global__ __launch_bounds__(256) void gram_kernel(
    const _Float16* __restrict__ xbuf,  // [B,N,64]
    const float*    __restrict__ sq,    // [B,N]
    const float*    __restrict__ beta,  // [1]
    float*          __restrict__ out)   // [B,N,N]
{
    const int tid  = threadIdx.x;
    const int wid  = tid >> 6;
    const int lane = tid & 63;
    const int l15  = lane & 15;
    const int lg   = lane >> 4;
    const int b    = blockIdx.z;
    const int jb   = blockIdx.x * 512;
    const int rb0  = blockIdx.y * 128;
    const int wjb  = jb + wid * 128;

    const _Float16* xb  = xbuf + (size_t)b * NN * PC;
    const float*    sqb = sq + (size_t)b * NN;

    const float bs   = -beta[0] * 1.44269504088896f;
    const float m2bs = -2.f * bs;

    f16x8 bf[8][2];
    float tj[8];
#pragma unroll
    for (int jtf = 0; jtf < 8; ++jtf) {
        const int j = wjb + jtf * 16 + l15;
#pragma unroll
        for (int ks = 0; ks < 2; ++ks)
            bf[jtf][ks] = *reinterpret_cast<const f16x8*>(
                xb + (size_t)j * PC + ks * 32 + lg * 8);
        tj[jtf] = bs * sqb[j];
    }

    __shared__ float lds[4][16][132];

    for (int rep = 0; rep < REP_G; ++rep) {
        asm volatile("" ::: "memory");   // force full re-execution per rep

        for (int rbh = 0; rbh < 2; ++rbh) {
            const int rb = rb0 + rbh * 64;

            for (int sl = 0; sl < 4; ++sl) {
                const int ibase = rb + sl * 16;

                const f16x8 af0 = *reinterpret_cast<const f16x8*>(
                    xb + (size_t)(ibase + l15) * PC + lg * 8);
                const f16x8 af1 = *reinterpret_cast<const f16x8*>(
                    xb + (size_t)(ibase + l15) * PC + 32 + lg * 8);

                f32x4 acc[8];
#pragma unroll
                for (int jtf = 0; jtf < 8; ++jtf) {
                    f32x4 z = {0.f, 0.f, 0.f, 0.f};
                    acc[jtf] = __builtin_amdgcn_mfma_f32_16x16x32_f16(af0, bf[jtf][0], z, 0, 0, 0);
                }
#pragma unroll
                for (int jtf = 0; jtf < 8; ++jtf)
                    acc[jtf] = __builtin_amdgcn_mfma_f32_16x16x32_f16(af1, bf[jtf][1], acc[jtf], 0, 0, 0);

                const f32x4 sv = *reinterpret_cast<const f32x4*>(sqb + ibase + lg * 4);

#pragma unroll
                for (int jtf = 0; jtf < 8; ++jtf) {
#pragma unroll
                    for (int r = 0; r < 4; ++r) {
                        const float ti = bs * sv[r];
                        float arg = fminf(fmaf(m2bs, acc[jtf][r], ti + tj[jtf]), 0.f);
                        lds[wid][lg * 4 + r][jtf * 16 + l15] = __builtin_amdgcn_exp2f(arg);
                    }
                }

#pragma unroll
                for (int k = 0; k < 8; ++k) {
                    const int row = 2 * k + (lane >> 5);
                    const int col = (lane & 31) * 4;
                    const f32x4 v = *reinterpret_cast<const f32x4*>(&lds[wid][row][col]);
                    __builtin_nontemporal_store(
                        v, reinterpret_cast<f32x4*>(
                               out + ((size_t)(b * NN + ibase + row)) * NN + wjb + col));
                }
            }
        }
    }
}

extern "C" void kernel_launch(void* const* d_in, const int* in_sizes, int n_in,
                              void* d_out, int out_size, void* d_ws, size_t ws_size,
                              hipStream_t stream) {
    const float* pos_bot = (const float*)d_in[0];
    const float* corr    = (const float*)d_in[1];
    const float* Wp      = (const float*)d_in[2];
    const float* bp      = (const float*)d_in[3];
    const float* Wv      = (const float*)d_in[4];
    const float* bv      = (const float*)d_in[5];
    const float* beta    = (const float*)d_in[6];

    float* out = (float*)d_out;                       // kernel [B,N,N]
    float* eqF = out + (size_t)BB * NN * NN;          // equation_F [B,N,128]

    _Float16* xbuf = (_Float16*)d_ws;                 // 2 MB
    float* sq = (float*)((char*)d_ws + (size_t)BB * NN * PC * sizeof(_Float16));

    proj_kernel<<<dim3(NN / 16, 2 * BB), 256, 0, stream>>>(
        pos_bot, corr, Wp, bp, Wv, bv, xbuf, sq, eqF);

    gram_kernel<<<dim3(NN / 512, NN / 128, BB), 256, 0, stream>>>(
        xbuf, sq, beta, out);
}

// Round 16
// 73.477 us; speedup vs baseline: 7.7732x; 7.7732x over previous
//
#include <hip/hip_runtime.h>
#include <hip/hip_bf16.h>

typedef _Float16 f16x8 __attribute__((ext_vector_type(8)));
typedef _Float16 f16x4 __attribute__((ext_vector_type(4)));
typedef float    f32x4 __attribute__((ext_vector_type(4)));

constexpr int BB = 4;
constexpr int CH = 128;
constexpr int PC = 64;
constexpr int NN = 4096;

// ---------------------------------------------------------------------------
// proj, LDS-staged: r15 counters showed the old proj was latency-bound
// (1.39 TB/s, VALUBusy 7%, 16 KB-strided scalar gathers): ~28 us cold.
// New: stage the input tile with fully-coalesced f32x4 row loads into LDS,
// then build fragments from LDS. Identical MFMA math -> identical outputs.
// grid (N/64, 2*B) = (64, 8) = 512 blocks; role = y>>2 (0: pos+sq, 1: val).
// Each block: 64 positions; wave w owns 16 positions, all output channels.
// ---------------------------------------------------------------------------
__global__ __launch_bounds__(256) void proj_kernel(
    const float* __restrict__ pos_bot,  // [B,64,N]
    const float* __restrict__ corr,     // [B,128,N]
    const float* __restrict__ Wp,       // [64,64]
    const float* __restrict__ bp,       // [64]
    const float* __restrict__ Wv,       // [128,128]
    const float* __restrict__ bv,       // [128]
    _Float16* __restrict__ xbuf,        // [B,N,64]
    float*    __restrict__ sq,          // [B,N]
    float*    __restrict__ eqF)         // [B,N,128]
{
    const int tid  = threadIdx.x;
    const int wid  = tid >> 6;
    const int lane = tid & 63;
    const int l15  = lane & 15;
    const int lg   = lane >> 4;
    const int b    = blockIdx.y & 3;
    const int role = blockIdx.y >> 2;
    const int n0   = blockIdx.x * 64;

    // [channel][n] tile; pad 68 keeps every row 16-B aligned for f32x4 ops.
    __shared__ float tile[128][68];

    const int nb = wid * 16;            // wave's n-group within the tile
    const int n  = n0 + nb + l15;

    if (role == 0) {
        // ---- stage pos_bot[b, 0:64, n0:n0+64] (coalesced rows) ----
        {
            const int r = tid >> 2, p = tid & 3;
            const float* src = pos_bot + ((size_t)(b * PC + r)) * NN + n0 + p * 16;
            float* dst = &tile[r][p * 16];
#pragma unroll
            for (int i = 0; i < 4; ++i)
                *reinterpret_cast<f32x4*>(dst + i * 4) =
                    *reinterpret_cast<const f32x4*>(src + i * 4);
        }
        __syncthreads();

        // ---- pos projection: x~ = f16(Wp @ pos + bp), sq = ||x~||^2 ----
        f16x8 pb[2];
#pragma unroll
        for (int ks = 0; ks < 2; ++ks) {
            f16x8 g;
#pragma unroll
            for (int e = 0; e < 8; ++e)
                g[e] = (_Float16)tile[ks * 32 + lg * 8 + e][nb + l15];
            pb[ks] = g;
        }

        float partial = 0.f;
#pragma unroll
        for (int mt = 0; mt < 4; ++mt) {
            f32x4 acc = {0.f, 0.f, 0.f, 0.f};
#pragma unroll
            for (int ks = 0; ks < 2; ++ks) {
                const float* wp = Wp + (mt * 16 + l15) * PC + ks * 32 + lg * 8;
                f32x4 w0 = *reinterpret_cast<const f32x4*>(wp);
                f32x4 w1 = *reinterpret_cast<const f32x4*>(wp + 4);
                f16x8 f;
#pragma unroll
                for (int e = 0; e < 4; ++e) { f[e] = (_Float16)w0[e]; f[e + 4] = (_Float16)w1[e]; }
                acc = __builtin_amdgcn_mfma_f32_16x16x32_f16(f, pb[ks], acc, 0, 0, 0);
            }
            f16x4 h4;
#pragma unroll
            for (int r = 0; r < 4; ++r) {
                const float v = acc[r] + bp[mt * 16 + lg * 4 + r];
                const _Float16 h = (_Float16)v;
                h4[r] = h;
                const float hf = (float)h;
                partial = fmaf(hf, hf, partial);
            }
            *reinterpret_cast<f16x4*>(xbuf + ((size_t)(b * NN + n)) * PC + mt * 16 + lg * 4) = h4;
        }
        partial += __shfl_xor(partial, 16);   // reduce across lg groups
        partial += __shfl_xor(partial, 32);
        if (lg == 0) sq[b * NN + n] = partial;
        return;
    }

    // ---- stage corr[b, 0:128, n0:n0+64] (coalesced rows) ----
#pragma unroll
    for (int u = 0; u < 2; ++u) {
        const int unit = tid + u * 256;
        const int r = unit >> 2, p = unit & 3;
        const float* src = corr + ((size_t)(b * CH + r)) * NN + n0 + p * 16;
        float* dst = &tile[r][p * 16];
#pragma unroll
        for (int i = 0; i < 4; ++i)
            *reinterpret_cast<f32x4*>(dst + i * 4) =
                *reinterpret_cast<const f32x4*>(src + i * 4);
    }
    __syncthreads();

    // ---- value projection: eqF = Wv @ corr + bv ----
    f16x8 cb[4];
#pragma unroll
    for (int ks = 0; ks < 4; ++ks) {
        f16x8 g;
#pragma unroll
        for (int e = 0; e < 8; ++e)
            g[e] = (_Float16)tile[ks * 32 + lg * 8 + e][nb + l15];
        cb[ks] = g;
    }
#pragma unroll
    for (int ot = 0; ot < 8; ++ot) {
        f32x4 acc = {0.f, 0.f, 0.f, 0.f};
#pragma unroll
        for (int ks = 0; ks < 4; ++ks) {
            const float* wv = Wv + (ot * 16 + l15) * CH + ks * 32 + lg * 8;
            f32x4 w0 = *reinterpret_cast<const f32x4*>(wv);
            f32x4 w1 = *reinterpret_cast<const f32x4*>(wv + 4);
            f16x8 f;
#pragma unroll
            for (int e = 0; e < 4; ++e) { f[e] = (_Float16)w0[e]; f[e + 4] = (_Float16)w1[e]; }
            acc = __builtin_amdgcn_mfma_f32_16x16x32_f16(f, cb[ks], acc, 0, 0, 0);
        }
        f32x4 o4;
#pragma unroll
        for (int r = 0; r < 4; ++r) o4[r] = acc[r] + bv[ot * 16 + lg * 4 + r];
        __builtin_nontemporal_store(
            o4, reinterpret_cast<f32x4*>(eqF + ((size_t)(b * NN + n)) * CH + ot * 16 + lg * 4));
    }
}

// ---------------------------------------------------------------------------
// gram: unchanged r14 single-generation version (measured steady-state at
// the 6.85 TB/s write floor; ~38-40 us single pass). 1024 blocks, block =
// 128i x 512j, bf prologue amortized over 2 row-strips, private-LDS
// transpose, 512 B-contiguous full-line NT stores, zero main-loop barriers.
// ---------------------------------------------------------------------------
__global__ __launch_bounds__(256) void gram_kernel(
    const _Float16* __restrict__ xbuf,  // [B,N,64]
    const float*    __restrict__ sq,    // [B,N]
    const float*    __restrict__ beta,  // [1]
    float*          __restrict__ out)   // [B,N,N]
{
    const int tid  = threadIdx.x;
    const int wid  = tid >> 6;
    const int lane = tid & 63;
    const int l15  = lane & 15;
    const int lg   = lane >> 4;
    const int b    = blockIdx.z;
    const int jb   = blockIdx.x * 512;
    const int rb0  = blockIdx.y * 128;
    const int wjb  = jb + wid * 128;

    const _Float16* xb  = xbuf + (size_t)b * NN * PC;
    const float*    sqb = sq + (size_t)b * NN;

    const float bs   = -beta[0] * 1.44269504088896f;  // exp(-b*d2)=exp2(bs*d2)
    const float m2bs = -2.f * bs;

    f16x8 bf[8][2];
    float tj[8];
#pragma unroll
    for (int jtf = 0; jtf < 8; ++jtf) {
        const int j = wjb + jtf * 16 + l15;
#pragma unroll
        for (int ks = 0; ks < 2; ++ks)
            bf[jtf][ks] = *reinterpret_cast<const f16x8*>(
                xb + (size_t)j * PC + ks * 32 + lg * 8);
        tj[jtf] = bs * sqb[j];
    }

    __shared__ float lds[4][16][132];   // per-wave private quadrant

    for (int rbh = 0; rbh < 2; ++rbh) {
        const int rb = rb0 + rbh * 64;

        for (int sl = 0; sl < 4; ++sl) {
            const int ibase = rb + sl * 16;

            const f16x8 af0 = *reinterpret_cast<const f16x8*>(
                xb + (size_t)(ibase + l15) * PC + lg * 8);
            const f16x8 af1 = *reinterpret_cast<const f16x8*>(
                xb + (size_t)(ibase + l15) * PC + 32 + lg * 8);

            f32x4 acc[8];
#pragma unroll
            for (int jtf = 0; jtf < 8; ++jtf) {
                f32x4 z = {0.f, 0.f, 0.f, 0.f};
                acc[jtf] = __builtin_amdgcn_mfma_f32_16x16x32_f16(af0, bf[jtf][0], z, 0, 0, 0);
            }
#pragma unroll
            for (int jtf = 0; jtf < 8; ++jtf)
                acc[jtf] = __builtin_amdgcn_mfma_f32_16x16x32_f16(af1, bf[jtf][1], acc[jtf], 0, 0, 0);

            const f32x4 sv = *reinterpret_cast<const f32x4*>(sqb + ibase + lg * 4);

#pragma unroll
            for (int jtf = 0; jtf < 8; ++jtf) {
#pragma unroll
                for (int r = 0; r < 4; ++r) {
                    const float ti = bs * sv[r];
                    float arg = fminf(fmaf(m2bs, acc[jtf][r], ti + tj[jtf]), 0.f);
                    lds[wid][lg * 4 + r][jtf * 16 + l15] = __builtin_amdgcn_exp2f(arg);
                }
            }

#pragma unroll
            for (int k = 0; k < 8; ++k) {
                const int row = 2 * k + (lane >> 5);
                const int col = (lane & 31) * 4;
                const f32x4 v = *reinterpret_cast<const f32x4*>(&lds[wid][row][col]);
                __builtin_nontemporal_store(
                    v, reinterpret_cast<f32x4*>(
                           out + ((size_t)(b * NN + ibase + row)) * NN + wjb + col));
            }
        }
    }
}

extern "C" void kernel_launch(void* const* d_in, const int* in_sizes, int n_in,
                              void* d_out, int out_size, void* d_ws, size_t ws_size,
                              hipStream_t stream) {
    const float* pos_bot = (const float*)d_in[0];
    const float* corr    = (const float*)d_in[1];
    const float* Wp      = (const float*)d_in[2];
    const float* bp      = (const float*)d_in[3];
    const float* Wv      = (const float*)d_in[4];
    const float* bv      = (const float*)d_in[5];
    const float* beta    = (const float*)d_in[6];

    float* out = (float*)d_out;                       // kernel [B,N,N]
    float* eqF = out + (size_t)BB * NN * NN;          // equation_F [B,N,128]

    _Float16* xbuf = (_Float16*)d_ws;                 // 2 MB
    float* sq = (float*)((char*)d_ws + (size_t)BB * NN * PC * sizeof(_Float16));

    proj_kernel<<<dim3(NN / 64, 2 * BB), 256, 0, stream>>>(
        pos_bot, corr, Wp, bp, Wv, bv, xbuf, sq, eqF);

    gram_kernel<<<dim3(NN / 512, NN / 128, BB), 256, 0, stream>>>(
        xbuf, sq, beta, out);
}